// Round 5
// baseline (125.585 us; speedup 1.0000x reference)
//
#include <hip/hip_runtime.h>
#include <hip/hip_bf16.h>

// Problem constants (from reference)
#define BATCH   16384
#define C_SEL   32
#define C_TOTAL 64
#define IN_F    128
#define OUT_F   128

#define BM      64    // batch rows per job
#define NGRP    32    // mtile groups (blocks per channel)
#define NJOBS   8     // jobs per block:  NGRP*NJOBS*BM == BATCH

typedef __bf16 bf16x8 __attribute__((ext_vector_type(8)));
typedef float  f32x4  __attribute__((ext_vector_type(4)));

__device__ __forceinline__ bf16x8 cvt_bf16x8(const float4 f0, const float4 f1) {
    bf16x8 a;
    a[0] = (__bf16)f0.x; a[1] = (__bf16)f0.y; a[2] = (__bf16)f0.z; a[3] = (__bf16)f0.w;
    a[4] = (__bf16)f1.x; a[5] = (__bf16)f1.y; a[6] = (__bf16)f1.z; a[7] = (__bf16)f1.w;
    return a;
}

__global__ __launch_bounds__(256, 4) void pl_mfma_kernel(
    const float* __restrict__ inp,       // (BATCH, C_SEL, IN_F)
    const float* __restrict__ weight,    // (C_TOTAL, OUT_F, IN_F)
    const float* __restrict__ bias,      // (C_TOTAL, OUT_F)
    const int*   __restrict__ channels,  // (C_SEL,)
    float*       __restrict__ out)       // (BATCH, C_SEL, OUT_F)
{
    // W[ch] as bf16 [128][128] = 32 KB; bank-conflict-free via 16B-unit XOR swizzle.
    __shared__ __bf16 ldsW[OUT_F * IN_F];
    __shared__ alignas(16) float ldsB[OUT_F];   // bias (512 B)

    const int bid = blockIdx.x;          // 1024 blocks
    const int c   = bid & 31;            // channel fastest
    const int g   = bid >> 5;            // mtile group 0..31
    const int ch  = channels[c];

    const int t  = threadIdx.x;
    const int w  = t >> 6;               // wave 0..3 -> batch rows [w*16, w*16+16)
    const int l  = t & 63;
    const int lr = l & 15;               // In-fragment: batch row; W-fragment: out feature
    const int lg = l >> 4;               // k-group 0..3

    // per-lane A base (floats): job j adds j*JSTRIDE
    const size_t JSTRIDE = (size_t)NGRP * BM * C_SEL * IN_F;   // 8,388,608 floats
    const float* abase = inp + (size_t)g * BM * C_SEL * IN_F
                       + ((size_t)(w * 16 + lr) * C_SEL + (size_t)c) * IN_F + lg * 8;

    // ---- prologue: issue job 0 and job 1 A-loads (fire HBM early) ----
    float4 raA[8], raB[8];
    #pragma unroll
    for (int ks = 0; ks < 4; ++ks) {
        raA[2 * ks]     = *reinterpret_cast<const float4*>(abase + ks * 32);
        raA[2 * ks + 1] = *reinterpret_cast<const float4*>(abase + ks * 32 + 4);
    }
    #pragma unroll
    for (int ks = 0; ks < 4; ++ks) {
        raB[2 * ks]     = *reinterpret_cast<const float4*>(abase + JSTRIDE + ks * 32);
        raB[2 * ks + 1] = *reinterpret_cast<const float4*>(abase + JSTRIDE + ks * 32 + 4);
    }

    // ---- stage W[ch] fp32 -> bf16 into LDS once (swizzled 16B units) ----
    const float* wsrc = weight + (size_t)ch * (OUT_F * IN_F);
    #pragma unroll
    for (int i = 0; i < 8; ++i) {
        const int fidx = i * 2048 + t * 8;
        const int row  = fidx >> 7;
        const int u    = (fidx & 127) >> 3;
        const float4 f0 = *reinterpret_cast<const float4*>(wsrc + fidx);
        const float4 f1 = *reinterpret_cast<const float4*>(wsrc + fidx + 4);
        const int up = u ^ (row & 7);
        *reinterpret_cast<bf16x8*>(&ldsW[row * IN_F + up * 8]) = cvt_bf16x8(f0, f1);
    }

    // ---- stage bias into LDS once ----
    if (t < 32) {
        const float4 bv = *reinterpret_cast<const float4*>(bias + (size_t)ch * OUT_F + t * 4);
        *reinterpret_cast<float4*>(&ldsB[t * 4]) = bv;
    }

    __syncthreads();

    // per-lane output base (floats): lane writes float4 at o = nt*16 + lg*4, m = base + lr
    float* obase = out + (size_t)g * BM * C_SEL * OUT_F
                 + ((size_t)(w * 16 + lr) * C_SEL + (size_t)c) * OUT_F + lg * 4;

    // ---- job loop, manually 2x-unrolled so raA/raB indexing stays static ----
    #pragma unroll
    for (int jj = 0; jj < NJOBS; jj += 2) {
        // ===== even job jj (consumes raA) =====
        {
            // acc init = bias (D row = out feature o = nt*16 + lg*4 + j)
            f32x4 acc[8];
            #pragma unroll
            for (int nt = 0; nt < 8; ++nt)
                acc[nt] = *reinterpret_cast<const f32x4*>(&ldsB[nt * 16 + lg * 4]);

            #pragma unroll
            for (int ks = 0; ks < 4; ++ks) {
                const bf16x8 a_in = cvt_bf16x8(raA[2 * ks], raA[2 * ks + 1]);  // counted vmcnt wait
                #pragma unroll
                for (int nt = 0; nt < 8; ++nt) {
                    const int row = nt * 16 + lr;                 // out feature (W row)
                    const int u   = (ks * 4 + lg) ^ (lr & 7);     // swizzled 16B unit
                    const bf16x8 w8 = *reinterpret_cast<const bf16x8*>(&ldsW[row * IN_F + u * 8]);
                    // D[o][m] = W * In^T : W is A-operand, In is B-operand
                    acc[nt] = __builtin_amdgcn_mfma_f32_16x16x32_bf16(w8, a_in, acc[nt], 0, 0, 0);
                }
            }

            // prefetch job jj+2 into raA (raA fully consumed above)
            if (jj + 2 < NJOBS) {
                const float* p = abase + (size_t)(jj + 2) * JSTRIDE;
                #pragma unroll
                for (int ks = 0; ks < 4; ++ks) {
                    raA[2 * ks]     = *reinterpret_cast<const float4*>(p + ks * 32);
                    raA[2 * ks + 1] = *reinterpret_cast<const float4*>(p + ks * 32 + 4);
                }
            }

            // epilogue: 8 fully-coalesced dwordx4 stores (bias already in acc)
            float* o = obase + (size_t)jj * JSTRIDE;
            #pragma unroll
            for (int nt = 0; nt < 8; ++nt) {
                *reinterpret_cast<float4*>(o + nt * 16) =
                    *reinterpret_cast<const float4*>(&acc[nt]);
            }
        }
        // ===== odd job jj+1 (consumes raB) =====
        {
            f32x4 acc[8];
            #pragma unroll
            for (int nt = 0; nt < 8; ++nt)
                acc[nt] = *reinterpret_cast<const f32x4*>(&ldsB[nt * 16 + lg * 4]);

            #pragma unroll
            for (int ks = 0; ks < 4; ++ks) {
                const bf16x8 a_in = cvt_bf16x8(raB[2 * ks], raB[2 * ks + 1]);
                #pragma unroll
                for (int nt = 0; nt < 8; ++nt) {
                    const int row = nt * 16 + lr;
                    const int u   = (ks * 4 + lg) ^ (lr & 7);
                    const bf16x8 w8 = *reinterpret_cast<const bf16x8*>(&ldsW[row * IN_F + u * 8]);
                    acc[nt] = __builtin_amdgcn_mfma_f32_16x16x32_bf16(w8, a_in, acc[nt], 0, 0, 0);
                }
            }

            if (jj + 3 < NJOBS) {
                const float* p = abase + (size_t)(jj + 3) * JSTRIDE;
                #pragma unroll
                for (int ks = 0; ks < 4; ++ks) {
                    raB[2 * ks]     = *reinterpret_cast<const float4*>(p + ks * 32);
                    raB[2 * ks + 1] = *reinterpret_cast<const float4*>(p + ks * 32 + 4);
                }
            }

            float* o = obase + (size_t)(jj + 1) * JSTRIDE;
            #pragma unroll
            for (int nt = 0; nt < 8; ++nt) {
                *reinterpret_cast<float4*>(o + nt * 16) =
                    *reinterpret_cast<const float4*>(&acc[nt]);
            }
        }
    }
}

extern "C" void kernel_launch(void* const* d_in, const int* in_sizes, int n_in,
                              void* d_out, int out_size, void* d_ws, size_t ws_size,
                              hipStream_t stream) {
    const float* inp      = (const float*)d_in[0];
    const float* weight   = (const float*)d_in[1];
    const float* bias     = (const float*)d_in[2];
    const int*   channels = (const int*)d_in[3];
    float*       out      = (float*)d_out;

    dim3 grid(C_SEL * NGRP);   // 1024 blocks, channel-fastest
    dim3 block(256);
    pl_mfma_kernel<<<grid, block, 0, stream>>>(inp, weight, bias, channels, out);
}